// Round 1
// baseline (181.568 us; speedup 1.0000x reference)
//
#include <hip/hip_runtime.h>
#include <math.h>

#define BB 1024
#define NN 128
#define DD 128
#define GG 512   // 4*D

__device__ __forceinline__ float sigmoidf_(float x) { return 1.0f / (1.0f + expf(-x)); }

// ---------------------------------------------------------------------------
// k_prep: blocks 0..63 build Wc[512][128] = W_ih[:, :128] + W_hh.
// blocks 64..67: compute biasv = b_ih+b_hh, h1/c1 (step-0 LSTM from biases),
// and gbase[512] = biasv + Wc·h1 (each block does 128 of the 512 rows).
// ---------------------------------------------------------------------------
__global__ __launch_bounds__(256) void k_prep(
    const float* __restrict__ W_ih, const float* __restrict__ W_hh,
    const float* __restrict__ b_ih, const float* __restrict__ b_hh,
    float* __restrict__ Wc, float* __restrict__ biasv, float* __restrict__ gbase,
    float* __restrict__ h1, float* __restrict__ c1) {
  int b = blockIdx.x, t = threadIdx.x;
  if (b < 64) {
    int base = b * 1024;
    for (int i = t; i < 1024; i += 256) {
      int idx = base + i;
      int j = idx >> 7, d = idx & 127;
      Wc[idx] = W_ih[(j << 8) + d] + W_hh[idx];   // W_hh[j*128+d] == W_hh[idx]
    }
  } else {
    __shared__ float bv[GG];
    __shared__ float h1l[DD];
    for (int j = t; j < GG; j += 256) bv[j] = b_ih[j] + b_hh[j];
    __syncthreads();
    if (t < DD) {
      // gate order i,f,g,o ; h=c=0 at step 0
      float cc = sigmoidf_(bv[t]) * tanhf(bv[256 + t]);
      float hh = sigmoidf_(bv[384 + t]) * tanhf(cc);
      h1l[t] = cc;   // reuse as temp? no — keep separate
      h1l[t] = hh;
      if (b == 64) { c1[t] = cc; h1[t] = hh; }
    }
    if (b == 64) for (int j = t; j < GG; j += 256) biasv[j] = bv[j];
    __syncthreads();
    int j0 = (b - 64) * 128;
    if (t < 128) {
      int j = j0 + t;
      float acc = bv[j];
      const float* wi = W_ih + (j << 8);
      const float* wh = W_hh + (j << 7);
      #pragma unroll 8
      for (int d = 0; d < DD; ++d) acc = fmaf(wi[d] + wh[d], h1l[d], acc);
      gbase[j] = acc;
    }
  }
}

// ---------------------------------------------------------------------------
// k_attn: one block (128 threads) per molecule.
// e[n] = y[n,:]·q (per-row wave reduce), masked softmax, r = sum a[n] y[n,:].
// q source: broadcast vector (step 0) or transposed [d][B] (steps 1,2).
// is_final: compute out[m] = (q·Wm[:128] + r·Wm[128:] + bm)*sd + mn instead of rT.
// ---------------------------------------------------------------------------
__global__ __launch_bounds__(128) void k_attn(
    const float* __restrict__ y, const int* __restrict__ lengths,
    const float* __restrict__ qsrc, int q_bcast,
    float* __restrict__ rT,
    const float* __restrict__ Wm, const float* __restrict__ bm,
    const float* __restrict__ mn, const float* __restrict__ sd,
    float* __restrict__ out, int is_final) {
  __shared__ float el[NN];
  __shared__ float al[NN];
  __shared__ float red[4];
  int t = threadIdx.x;          // 0..127
  int lane = t & 63, wid = t >> 6;
  int m = blockIdx.x;
  int len = lengths[m];
  const float* yb = y + (size_t)m * (NN * DD);

  float qlo, qhi, qt;
  if (q_bcast) { qlo = qsrc[lane]; qhi = qsrc[64 + lane]; qt = qsrc[t]; }
  else { qlo = qsrc[lane * BB + m]; qhi = qsrc[(64 + lane) * BB + m]; qt = qsrc[t * BB + m]; }

  // e-pass: wave `wid` handles rows nb+wid (wave-uniform predicate)
  for (int nb = 0; nb < len; nb += 2) {
    int n = nb + wid;
    if (n < len) {
      const float* yr = yb + n * DD;
      float p = yr[lane] * qlo + yr[64 + lane] * qhi;
      #pragma unroll
      for (int s = 1; s < 64; s <<= 1) p += __shfl_xor(p, s, 64);
      if (lane == 0) el[n] = p;
    }
  }
  __syncthreads();

  // softmax over el[0..len)
  float e = (t < len) ? el[t] : -1e30f;
  float v = e;
  #pragma unroll
  for (int s = 1; s < 64; s <<= 1) v = fmaxf(v, __shfl_xor(v, s, 64));
  if (lane == 0) red[wid] = v;
  __syncthreads();
  float mx = fmaxf(red[0], red[1]);
  float a = (t < len) ? expf(e - mx) : 0.0f;
  al[t] = a;
  float sum = a;
  #pragma unroll
  for (int s = 1; s < 64; s <<= 1) sum += __shfl_xor(sum, s, 64);
  if (lane == 0) red[2 + wid] = sum;
  __syncthreads();
  float invZ = 1.0f / (red[2] + red[3]);

  // r-pass: thread t = feature d, coalesced global re-read (L2/L3-hot)
  float racc = 0.0f;
  for (int n = 0; n < len; ++n) racc = fmaf(al[n], yb[n * DD + t], racc);
  racc *= invZ;

  if (!is_final) {
    rT[t * BB + m] = racc;
  } else {
    float part = Wm[t] * qt + Wm[DD + t] * racc;
    #pragma unroll
    for (int s = 1; s < 64; s <<= 1) part += __shfl_xor(part, s, 64);
    if (lane == 0) red[wid] = part;
    __syncthreads();
    if (t == 0) out[m] = (red[0] + red[1] + bm[0]) * sd[0] + mn[0];
  }
}

// ---------------------------------------------------------------------------
// k_lstm: lane = molecule. Wave-uniform gate row jb (readfirstlane -> s_load
// weights), x[128] in VGPRs loaded coalesced from transposed [d][B] buffers.
// step1 (h_inT==null): acc = gbase + Wr·r  (K=128)
// step2:               acc = biasv + Wc·h + Wr·r (K=256, two passes reusing x)
// ---------------------------------------------------------------------------
__global__ __launch_bounds__(256) void k_lstm(
    const float* __restrict__ W_ih, const float* __restrict__ Wc,
    const float* __restrict__ gb,
    const float* __restrict__ h_inT,
    const float* __restrict__ c_in, int c_bcast,
    const float* __restrict__ rT,
    float* __restrict__ h_outT, float* __restrict__ c_outT) {
  int lane = threadIdx.x & 63, wid = threadIdx.x >> 6;
  int m = (blockIdx.x << 6) + lane;
  int jb = __builtin_amdgcn_readfirstlane((blockIdx.y << 2) + wid);  // 0..127

  float x[DD];
  float ai = gb[jb], af = gb[128 + jb], ag = gb[256 + jb], ao = gb[384 + jb];

  if (h_inT) {
    #pragma unroll
    for (int d = 0; d < DD; ++d) x[d] = h_inT[d * BB + m];
    const float* w0 = Wc + jb * DD;
    const float* w1 = Wc + (128 + jb) * DD;
    const float* w2 = Wc + (256 + jb) * DD;
    const float* w3 = Wc + (384 + jb) * DD;
    #pragma unroll
    for (int d = 0; d < DD; ++d) {
      float xd = x[d];
      ai = fmaf(w0[d], xd, ai); af = fmaf(w1[d], xd, af);
      ag = fmaf(w2[d], xd, ag); ao = fmaf(w3[d], xd, ao);
    }
  }

  #pragma unroll
  for (int d = 0; d < DD; ++d) x[d] = rT[d * BB + m];
  {
    const float* w0 = W_ih + jb * 256 + 128;
    const float* w1 = W_ih + (128 + jb) * 256 + 128;
    const float* w2 = W_ih + (256 + jb) * 256 + 128;
    const float* w3 = W_ih + (384 + jb) * 256 + 128;
    #pragma unroll
    for (int d = 0; d < DD; ++d) {
      float xd = x[d];
      ai = fmaf(w0[d], xd, ai); af = fmaf(w1[d], xd, af);
      ag = fmaf(w2[d], xd, ag); ao = fmaf(w3[d], xd, ao);
    }
  }

  float cin = c_bcast ? c_in[jb] : c_in[jb * BB + m];
  float cc = fmaf(sigmoidf_(af), cin, sigmoidf_(ai) * tanhf(ag));
  float hh = sigmoidf_(ao) * tanhf(cc);
  h_outT[jb * BB + m] = hh;
  if (c_outT) c_outT[jb * BB + m] = cc;
}

// ---------------------------------------------------------------------------
extern "C" void kernel_launch(void* const* d_in, const int* in_sizes, int n_in,
                              void* d_out, int out_size, void* d_ws, size_t ws_size,
                              hipStream_t stream) {
  const float* y    = (const float*)d_in[0];
  const int*   len  = (const int*)  d_in[1];
  const float* W_ih = (const float*)d_in[2];
  const float* W_hh = (const float*)d_in[3];
  const float* b_ih = (const float*)d_in[4];
  const float* b_hh = (const float*)d_in[5];
  const float* W_m  = (const float*)d_in[6];
  const float* b_m  = (const float*)d_in[7];
  const float* mean = (const float*)d_in[8];
  const float* sd   = (const float*)d_in[9];
  float* out = (float*)d_out;

  float* ws = (float*)d_ws;
  float* Wc    = ws;                 // 512*128
  float* biasv = ws + 65536;         // 512
  float* gbase = ws + 66048;         // 512
  float* h1    = ws + 66560;         // 128
  float* c1    = ws + 66688;         // 128
  float* rT    = ws + 66816;         // 128*1024  (r0 then r1)
  float* h2T   = ws + 197888;        // 128*1024
  float* c2T   = ws + 328960;        // 128*1024
  float* h3T   = ws + 460032;        // 128*1024

  k_prep<<<68, 256, 0, stream>>>(W_ih, W_hh, b_ih, b_hh, Wc, biasv, gbase, h1, c1);

  // step 0 attention: q = h1 (broadcast) -> r0
  k_attn<<<BB, 128, 0, stream>>>(y, len, h1, 1, rT, W_m, b_m, mean, sd, nullptr, 0);
  // step 1 LSTM: gates = gbase + Wr*r0 -> h2, c2
  k_lstm<<<dim3(BB / 64, 32), 256, 0, stream>>>(W_ih, Wc, gbase, nullptr, c1, 1, rT, h2T, c2T);
  // step 1 attention: q = h2 -> r1
  k_attn<<<BB, 128, 0, stream>>>(y, len, h2T, 0, rT, W_m, b_m, mean, sd, nullptr, 0);
  // step 2 LSTM: gates = biasv + Wc*h2 + Wr*r1 -> h3
  k_lstm<<<dim3(BB / 64, 32), 256, 0, stream>>>(W_ih, Wc, biasv, h2T, c2T, 0, rT, h3T, nullptr);
  // step 2 attention + final projection
  k_attn<<<BB, 128, 0, stream>>>(y, len, h3T, 0, nullptr, W_m, b_m, mean, sd, out, 1);
}

// Round 2
// 102.207 us; speedup vs baseline: 1.7765x; 1.7765x over previous
//
#include <hip/hip_runtime.h>
#include <math.h>

#define BB 1024
#define NN 128
#define DD 128
#define GG 512   // 4*D

__device__ __forceinline__ float sigmoidf_(float x) { return 1.0f / (1.0f + expf(-x)); }

// ---------------------------------------------------------------------------
// k_prep: blocks 0..63 build Wc[512][128] = W_ih[:, :128] + W_hh.
// blocks 64..67: biasv = b_ih+b_hh, h1/c1 (step-0 LSTM from biases),
// gbase[512] = biasv + Wc·h1 (each block does 128 of the 512 rows).
// ---------------------------------------------------------------------------
__global__ __launch_bounds__(256) void k_prep(
    const float* __restrict__ W_ih, const float* __restrict__ W_hh,
    const float* __restrict__ b_ih, const float* __restrict__ b_hh,
    float* __restrict__ Wc, float* __restrict__ biasv, float* __restrict__ gbase,
    float* __restrict__ h1, float* __restrict__ c1) {
  int b = blockIdx.x, t = threadIdx.x;
  if (b < 64) {
    int base = b * 1024;
    for (int i = t; i < 1024; i += 256) {
      int idx = base + i;
      int j = idx >> 7, d = idx & 127;
      Wc[idx] = W_ih[(j << 8) + d] + W_hh[idx];
    }
  } else {
    __shared__ float bv[GG];
    __shared__ float h1l[DD];
    for (int j = t; j < GG; j += 256) bv[j] = b_ih[j] + b_hh[j];
    __syncthreads();
    if (t < DD) {
      float cc = sigmoidf_(bv[t]) * tanhf(bv[256 + t]);
      float hh = sigmoidf_(bv[384 + t]) * tanhf(cc);
      h1l[t] = hh;
      if (b == 64) { c1[t] = cc; h1[t] = hh; }
    }
    if (b == 64) for (int j = t; j < GG; j += 256) biasv[j] = bv[j];
    __syncthreads();
    int j0 = (b - 64) * 128;
    if (t < 128) {
      int j = j0 + t;
      float acc = bv[j];
      const float* wi = W_ih + (j << 8);
      const float* wh = W_hh + (j << 7);
      #pragma unroll 8
      for (int d = 0; d < DD; ++d) acc = fmaf(wi[d] + wh[d], h1l[d], acc);
      gbase[j] = acc;
    }
  }
}

// ---------------------------------------------------------------------------
// k_attn v2: 256 threads (4 waves) per molecule.
// e-pass: 16-lane groups own 8 d's each -> 4 rows per wave per iteration,
//   unguarded float4 loads (rows < 128 always valid), 4-step group reduce.
// r-pass: wave w takes rows n ≡ w (mod 4), lane holds float2 of d,
//   4 independent accumulators, LDS combine.
// ---------------------------------------------------------------------------
__global__ __launch_bounds__(256) void k_attn(
    const float* __restrict__ y, const int* __restrict__ lengths,
    const float* __restrict__ qsrc, int q_bcast,
    float* __restrict__ rT,
    const float* __restrict__ Wm, const float* __restrict__ bm,
    const float* __restrict__ mn, const float* __restrict__ sd,
    float* __restrict__ out, int is_final) {
  __shared__ float ql[DD];
  __shared__ float el[NN];
  __shared__ float al[NN];
  __shared__ float rp[4][DD];
  __shared__ float red[8];

  int t = threadIdx.x, lane = t & 63, w = t >> 6;
  int m = blockIdx.x;
  int len = lengths[m];
  const float* yb = y + (size_t)m * (NN * DD);

  if (t < DD) ql[t] = q_bcast ? qsrc[t] : qsrc[t * BB + m];
  __syncthreads();

  // ---- e-pass ----
  int sub = lane & 15, g = lane >> 4;
  int d0 = sub << 3;
  float q0 = ql[d0], q1 = ql[d0 + 1], q2 = ql[d0 + 2], q3 = ql[d0 + 3];
  float q4 = ql[d0 + 4], q5 = ql[d0 + 5], q6 = ql[d0 + 6], q7 = ql[d0 + 7];

  int nit = (len + 15) >> 4;
  for (int it = 0; it < nit; ++it) {
    int n = (it << 4) + (w << 2) + g;       // n <= 127 always (valid memory)
    const float4* yr = (const float4*)(yb + n * DD + d0);
    float4 a = yr[0], b = yr[1];
    float plo = fmaf(a.x, q0, fmaf(a.y, q1, fmaf(a.z, q2, a.w * q3)));
    float phi = fmaf(b.x, q4, fmaf(b.y, q5, fmaf(b.z, q6, b.w * q7)));
    float p = plo + phi;
    #pragma unroll
    for (int s = 1; s < 16; s <<= 1) p += __shfl_xor(p, s, 64);
    if (sub == 0 && n < len) el[n] = p;
  }
  __syncthreads();

  // ---- softmax over el[0..len) (all 256 threads run the reductions) ----
  float e = (t < NN && t < len) ? el[t] : -3.0e38f;
  float v = e;
  #pragma unroll
  for (int s = 1; s < 64; s <<= 1) v = fmaxf(v, __shfl_xor(v, s, 64));
  if (lane == 0) red[w] = v;
  __syncthreads();
  float mx = fmaxf(red[0], red[1]);
  float a = (t < NN && t < len) ? expf(e - mx) : 0.0f;
  if (t < NN) al[t] = a;
  float ssum = a;
  #pragma unroll
  for (int s = 1; s < 64; s <<= 1) ssum += __shfl_xor(ssum, s, 64);
  if (lane == 0) red[4 + w] = ssum;
  __syncthreads();
  float invZ = 1.0f / (red[4] + red[5]);

  // ---- r-pass ----
  const float2* yb2 = (const float2*)yb;   // row stride = 64 float2
  float2 ac0 = {0.f, 0.f}, ac1 = {0.f, 0.f}, ac2 = {0.f, 0.f}, ac3 = {0.f, 0.f};
  int n = w;
  for (; n + 12 < len; n += 16) {
    float2 v0 = yb2[(n)      * 64 + lane];
    float2 v1 = yb2[(n + 4)  * 64 + lane];
    float2 v2 = yb2[(n + 8)  * 64 + lane];
    float2 v3 = yb2[(n + 12) * 64 + lane];
    float a0 = al[n], a1 = al[n + 4], a2 = al[n + 8], a3 = al[n + 12];
    ac0.x = fmaf(a0, v0.x, ac0.x); ac0.y = fmaf(a0, v0.y, ac0.y);
    ac1.x = fmaf(a1, v1.x, ac1.x); ac1.y = fmaf(a1, v1.y, ac1.y);
    ac2.x = fmaf(a2, v2.x, ac2.x); ac2.y = fmaf(a2, v2.y, ac2.y);
    ac3.x = fmaf(a3, v3.x, ac3.x); ac3.y = fmaf(a3, v3.y, ac3.y);
  }
  for (; n < len; n += 4) {
    float2 v0 = yb2[n * 64 + lane];
    float a0 = al[n];
    ac0.x = fmaf(a0, v0.x, ac0.x); ac0.y = fmaf(a0, v0.y, ac0.y);
  }
  ac0.x += ac1.x + ac2.x + ac3.x;
  ac0.y += ac1.y + ac2.y + ac3.y;
  rp[w][lane * 2] = ac0.x;
  rp[w][lane * 2 + 1] = ac0.y;
  __syncthreads();

  float r = 0.0f;
  if (t < DD) r = (rp[0][t] + rp[1][t] + rp[2][t] + rp[3][t]) * invZ;

  if (!is_final) {
    if (t < DD) rT[t * BB + m] = r;
  } else {
    float part = (t < DD) ? (Wm[t] * ql[t] + Wm[DD + t] * r) : 0.0f;
    #pragma unroll
    for (int s = 1; s < 64; s <<= 1) part += __shfl_xor(part, s, 64);
    if (lane == 0) red[w] = part;   // red[0..1] already consumed (barrier above)
    __syncthreads();
    if (t == 0) out[m] = (red[0] + red[1] + red[2] + red[3] + bm[0]) * sd[0] + mn[0];
  }
}

// ---------------------------------------------------------------------------
// k_lstm: lane = molecule. Wave-uniform gate row jb, x[128] in VGPRs loaded
// coalesced from transposed [d][B] buffers.
// step1 (h_inT==null): acc = gbase + Wr·r  (K=128)
// step2:               acc = biasv + Wc·h + Wr·r (K=256)
// ---------------------------------------------------------------------------
__global__ __launch_bounds__(256) void k_lstm(
    const float* __restrict__ W_ih, const float* __restrict__ Wc,
    const float* __restrict__ gb,
    const float* __restrict__ h_inT,
    const float* __restrict__ c_in, int c_bcast,
    const float* __restrict__ rT,
    float* __restrict__ h_outT, float* __restrict__ c_outT) {
  int lane = threadIdx.x & 63, wid = threadIdx.x >> 6;
  int m = (blockIdx.x << 6) + lane;
  int jb = __builtin_amdgcn_readfirstlane((blockIdx.y << 2) + wid);  // 0..127

  float x[DD];
  float ai = gb[jb], af = gb[128 + jb], ag = gb[256 + jb], ao = gb[384 + jb];

  if (h_inT) {
    #pragma unroll
    for (int d = 0; d < DD; ++d) x[d] = h_inT[d * BB + m];
    const float* w0 = Wc + jb * DD;
    const float* w1 = Wc + (128 + jb) * DD;
    const float* w2 = Wc + (256 + jb) * DD;
    const float* w3 = Wc + (384 + jb) * DD;
    #pragma unroll
    for (int d = 0; d < DD; ++d) {
      float xd = x[d];
      ai = fmaf(w0[d], xd, ai); af = fmaf(w1[d], xd, af);
      ag = fmaf(w2[d], xd, ag); ao = fmaf(w3[d], xd, ao);
    }
  }

  #pragma unroll
  for (int d = 0; d < DD; ++d) x[d] = rT[d * BB + m];
  {
    const float* w0 = W_ih + jb * 256 + 128;
    const float* w1 = W_ih + (128 + jb) * 256 + 128;
    const float* w2 = W_ih + (256 + jb) * 256 + 128;
    const float* w3 = W_ih + (384 + jb) * 256 + 128;
    #pragma unroll
    for (int d = 0; d < DD; ++d) {
      float xd = x[d];
      ai = fmaf(w0[d], xd, ai); af = fmaf(w1[d], xd, af);
      ag = fmaf(w2[d], xd, ag); ao = fmaf(w3[d], xd, ao);
    }
  }

  float cin = c_bcast ? c_in[jb] : c_in[jb * BB + m];
  float cc = fmaf(sigmoidf_(af), cin, sigmoidf_(ai) * tanhf(ag));
  float hh = sigmoidf_(ao) * tanhf(cc);
  h_outT[jb * BB + m] = hh;
  if (c_outT) c_outT[jb * BB + m] = cc;
}

// ---------------------------------------------------------------------------
extern "C" void kernel_launch(void* const* d_in, const int* in_sizes, int n_in,
                              void* d_out, int out_size, void* d_ws, size_t ws_size,
                              hipStream_t stream) {
  const float* y    = (const float*)d_in[0];
  const int*   len  = (const int*)  d_in[1];
  const float* W_ih = (const float*)d_in[2];
  const float* W_hh = (const float*)d_in[3];
  const float* b_ih = (const float*)d_in[4];
  const float* b_hh = (const float*)d_in[5];
  const float* W_m  = (const float*)d_in[6];
  const float* b_m  = (const float*)d_in[7];
  const float* mean = (const float*)d_in[8];
  const float* sd   = (const float*)d_in[9];
  float* out = (float*)d_out;

  float* ws = (float*)d_ws;
  float* Wc    = ws;                 // 512*128
  float* biasv = ws + 65536;         // 512
  float* gbase = ws + 66048;         // 512
  float* h1    = ws + 66560;         // 128
  float* c1    = ws + 66688;         // 128
  float* rT    = ws + 66816;         // 128*1024
  float* h2T   = ws + 197888;        // 128*1024
  float* c2T   = ws + 328960;        // 128*1024
  float* h3T   = ws + 460032;        // 128*1024

  k_prep<<<68, 256, 0, stream>>>(W_ih, W_hh, b_ih, b_hh, Wc, biasv, gbase, h1, c1);

  // step 0 attention: q = h1 (broadcast) -> r0
  k_attn<<<BB, 256, 0, stream>>>(y, len, h1, 1, rT, W_m, b_m, mean, sd, nullptr, 0);
  // step 1 LSTM: gates = gbase + Wr*r0 -> h2, c2
  k_lstm<<<dim3(BB / 64, 32), 256, 0, stream>>>(W_ih, Wc, gbase, nullptr, c1, 1, rT, h2T, c2T);
  // step 1 attention: q = h2 -> r1
  k_attn<<<BB, 256, 0, stream>>>(y, len, h2T, 0, rT, W_m, b_m, mean, sd, nullptr, 0);
  // step 2 LSTM: gates = biasv + Wc*h2 + Wr*r1 -> h3
  k_lstm<<<dim3(BB / 64, 32), 256, 0, stream>>>(W_ih, Wc, biasv, h2T, c2T, 0, rT, h3T, nullptr);
  // step 2 attention + final projection
  k_attn<<<BB, 256, 0, stream>>>(y, len, h3T, 0, nullptr, W_m, b_m, mean, sd, out, 1);
}

// Round 3
// 67.394 us; speedup vs baseline: 2.6941x; 1.5166x over previous
//
#include <hip/hip_runtime.h>
#include <math.h>

#define BB 1024
#define NN 128
#define DD 128
#define GG 512   // 4*D

__device__ __forceinline__ float sigmoidf_(float x) { return 1.0f / (1.0f + expf(-x)); }

// ---------------------------------------------------------------------------
// k_prep: blocks 0..63 build Wc[512][128] = W_ih[:, :128] + W_hh.
// blocks 64..67: biasv = b_ih+b_hh, h1/c1 (step-0 LSTM from biases),
// gbase[512] = biasv + Wc·h1.
// ---------------------------------------------------------------------------
__global__ __launch_bounds__(256) void k_prep(
    const float* __restrict__ W_ih, const float* __restrict__ W_hh,
    const float* __restrict__ b_ih, const float* __restrict__ b_hh,
    float* __restrict__ Wc, float* __restrict__ biasv, float* __restrict__ gbase,
    float* __restrict__ h1, float* __restrict__ c1) {
  int b = blockIdx.x, t = threadIdx.x;
  if (b < 64) {
    int base = b * 1024;
    for (int i = t; i < 1024; i += 256) {
      int idx = base + i;
      int j = idx >> 7, d = idx & 127;
      Wc[idx] = W_ih[(j << 8) + d] + W_hh[idx];
    }
  } else {
    __shared__ float bv[GG];
    __shared__ float h1l[DD];
    for (int j = t; j < GG; j += 256) bv[j] = b_ih[j] + b_hh[j];
    __syncthreads();
    if (t < DD) {
      float cc = sigmoidf_(bv[t]) * tanhf(bv[256 + t]);
      float hh = sigmoidf_(bv[384 + t]) * tanhf(cc);
      h1l[t] = hh;
      if (b == 64) { c1[t] = cc; h1[t] = hh; }
    }
    if (b == 64) for (int j = t; j < GG; j += 256) biasv[j] = bv[j];
    __syncthreads();
    int j0 = (b - 64) * 128;
    if (t < 128) {
      int j = j0 + t;
      float acc = bv[j];
      const float* wi = W_ih + (j << 8);
      const float* wh = W_hh + (j << 7);
      #pragma unroll 8
      for (int d = 0; d < DD; ++d) acc = fmaf(wi[d] + wh[d], h1l[d], acc);
      gbase[j] = acc;
    }
  }
}

// ---------------------------------------------------------------------------
// k_attn v3: 256 threads / molecule, SINGLE pass over y.
// 16-lane group (w,g) owns rows n = it*16 + w*4 + g, d-slice d0 = sub*8.
// y block kept in registers (8 iters x 2 float4). Clamped row index for
// n >= len (weight becomes exp(-3e38-mx) = 0). Softmax in-register; the
// x16 lane duplication of the sum is fixed by a single /16.
// ---------------------------------------------------------------------------
__global__ __launch_bounds__(256) void k_attn(
    const float* __restrict__ y, const int* __restrict__ lengths,
    const float* __restrict__ qsrc, int q_bcast,
    float* __restrict__ rT,
    const float* __restrict__ Wm, const float* __restrict__ bm,
    const float* __restrict__ mn, const float* __restrict__ sd,
    float* __restrict__ out, int is_final) {
  __shared__ float ql[DD];
  __shared__ float rp[16][DD];
  __shared__ float redm[4], reds[4], redf[4];

  int t = threadIdx.x, lane = t & 63, w = t >> 6;
  int sub = lane & 15, g = lane >> 4;
  int m = blockIdx.x;
  int len = lengths[m];
  const float* yb = y + (size_t)m * (NN * DD);
  int d0 = sub << 3;

  if (t < DD) ql[t] = q_bcast ? qsrc[t] : qsrc[t * BB + m];
  __syncthreads();

  float4 q0 = *(const float4*)&ql[d0];
  float4 q1 = *(const float4*)&ql[d0 + 4];

  float4 va[8], vb[8];
  float ee[8];
  int base_n = (w << 2) + g;

  #pragma unroll
  for (int it = 0; it < 8; ++it) {
    int n = (it << 4) + base_n;
    int nc = (n < len) ? n : (len - 1);
    const float4* yr = (const float4*)(yb + nc * DD + d0);
    va[it] = yr[0];
    vb[it] = yr[1];
    float p = fmaf(va[it].x, q0.x, fmaf(va[it].y, q0.y,
              fmaf(va[it].z, q0.z, fmaf(va[it].w, q0.w,
              fmaf(vb[it].x, q1.x, fmaf(vb[it].y, q1.y,
              fmaf(vb[it].z, q1.z, vb[it].w * q1.w)))))));
    #pragma unroll
    for (int s = 1; s < 16; s <<= 1) p += __shfl_xor(p, s, 64);
    ee[it] = (n < len) ? p : -3.0e38f;
  }

  // ---- softmax (in-register) ----
  float mloc = ee[0];
  #pragma unroll
  for (int it = 1; it < 8; ++it) mloc = fmaxf(mloc, ee[it]);
  #pragma unroll
  for (int s = 1; s < 64; s <<= 1) mloc = fmaxf(mloc, __shfl_xor(mloc, s, 64));
  if (lane == 0) redm[w] = mloc;
  __syncthreads();
  float mx = fmaxf(fmaxf(redm[0], redm[1]), fmaxf(redm[2], redm[3]));

  float a[8];
  float sl = 0.0f;
  #pragma unroll
  for (int it = 0; it < 8; ++it) { a[it] = expf(ee[it] - mx); sl += a[it]; }
  #pragma unroll
  for (int s = 1; s < 64; s <<= 1) sl += __shfl_xor(sl, s, 64);
  if (lane == 0) reds[w] = sl;
  __syncthreads();
  float invZ = 16.0f / (reds[0] + reds[1] + reds[2] + reds[3]);

  // ---- weighted sum from registers ----
  float4 r0 = {0.f, 0.f, 0.f, 0.f}, r1 = {0.f, 0.f, 0.f, 0.f};
  #pragma unroll
  for (int it = 0; it < 8; ++it) {
    float av = a[it];
    r0.x = fmaf(av, va[it].x, r0.x); r0.y = fmaf(av, va[it].y, r0.y);
    r0.z = fmaf(av, va[it].z, r0.z); r0.w = fmaf(av, va[it].w, r0.w);
    r1.x = fmaf(av, vb[it].x, r1.x); r1.y = fmaf(av, vb[it].y, r1.y);
    r1.z = fmaf(av, vb[it].z, r1.z); r1.w = fmaf(av, vb[it].w, r1.w);
  }
  int wg = (w << 2) | g;
  *(float4*)&rp[wg][d0] = r0;
  *(float4*)&rp[wg][d0 + 4] = r1;
  __syncthreads();

  float r_ = 0.0f;
  if (t < DD) {
    #pragma unroll
    for (int k = 0; k < 16; ++k) r_ += rp[k][t];
    r_ *= invZ;
    if (!is_final) rT[t * BB + m] = r_;
  }
  if (is_final) {
    float part = (t < DD) ? (Wm[t] * ql[t] + Wm[DD + t] * r_) : 0.0f;
    #pragma unroll
    for (int s = 1; s < 64; s <<= 1) part += __shfl_xor(part, s, 64);
    if (lane == 0) redf[w] = part;
    __syncthreads();
    if (t == 0) out[m] = (redf[0] + redf[1] + redf[2] + redf[3] + bm[0]) * sd[0] + mn[0];
  }
}

// ---------------------------------------------------------------------------
// k_lstm v3: 512 threads (8 waves), block = 64 molecules x 8 gate-row-groups.
// x panel staged in LDS once per phase (kills the 128x redundant L2 reads).
// Wave wid owns gate rows {jb, jb+128, jb+256, jb+384}, jb = by*8+wid,
// weights via wave-uniform (scalar) loads. lane = molecule.
// step1 (h_inT==null): acc = gbase + Wr.r   (K=128)
// step2:               acc = biasv + Wc.h + Wr.r (K=256, two LDS phases)
// ---------------------------------------------------------------------------
__global__ __launch_bounds__(512) void k_lstm(
    const float* __restrict__ W_ih, const float* __restrict__ Wc,
    const float* __restrict__ gb,
    const float* __restrict__ h_inT,
    const float* __restrict__ c_in, int c_bcast,
    const float* __restrict__ rT,
    float* __restrict__ h_outT, float* __restrict__ c_outT) {
  __shared__ float xl[DD * 64];
  int t = threadIdx.x;
  int ml = t & 63, wid = t >> 6;
  int m0 = blockIdx.x << 6;
  int m = m0 + ml;
  int jb = __builtin_amdgcn_readfirstlane((blockIdx.y << 3) + wid);  // 0..127

  float ai = gb[jb], af = gb[DD + jb], ag = gb[2 * DD + jb], ao = gb[3 * DD + jb];

  if (h_inT) {
    #pragma unroll
    for (int k = 0; k < 16; ++k) {
      int i = (k << 9) + t;
      xl[i] = h_inT[(i >> 6) * BB + m0 + (i & 63)];
    }
    __syncthreads();
    const float* w0 = Wc + jb * DD;
    const float* w1 = Wc + (128 + jb) * DD;
    const float* w2 = Wc + (256 + jb) * DD;
    const float* w3 = Wc + (384 + jb) * DD;
    #pragma unroll 8
    for (int d = 0; d < DD; ++d) {
      float xd = xl[(d << 6) + ml];
      ai = fmaf(w0[d], xd, ai); af = fmaf(w1[d], xd, af);
      ag = fmaf(w2[d], xd, ag); ao = fmaf(w3[d], xd, ao);
    }
    __syncthreads();   // all waves done reading before restage
  }

  #pragma unroll
  for (int k = 0; k < 16; ++k) {
    int i = (k << 9) + t;
    xl[i] = rT[(i >> 6) * BB + m0 + (i & 63)];
  }
  __syncthreads();
  {
    const float* w0 = W_ih + jb * 256 + 128;
    const float* w1 = W_ih + (128 + jb) * 256 + 128;
    const float* w2 = W_ih + (256 + jb) * 256 + 128;
    const float* w3 = W_ih + (384 + jb) * 256 + 128;
    #pragma unroll 8
    for (int d = 0; d < DD; ++d) {
      float xd = xl[(d << 6) + ml];
      ai = fmaf(w0[d], xd, ai); af = fmaf(w1[d], xd, af);
      ag = fmaf(w2[d], xd, ag); ao = fmaf(w3[d], xd, ao);
    }
  }

  float cin = c_bcast ? c_in[jb] : c_in[jb * BB + m];
  float cc = fmaf(sigmoidf_(af), cin, sigmoidf_(ai) * tanhf(ag));
  float hh = sigmoidf_(ao) * tanhf(cc);
  h_outT[jb * BB + m] = hh;
  if (c_outT) c_outT[jb * BB + m] = cc;
}

// ---------------------------------------------------------------------------
extern "C" void kernel_launch(void* const* d_in, const int* in_sizes, int n_in,
                              void* d_out, int out_size, void* d_ws, size_t ws_size,
                              hipStream_t stream) {
  const float* y    = (const float*)d_in[0];
  const int*   len  = (const int*)  d_in[1];
  const float* W_ih = (const float*)d_in[2];
  const float* W_hh = (const float*)d_in[3];
  const float* b_ih = (const float*)d_in[4];
  const float* b_hh = (const float*)d_in[5];
  const float* W_m  = (const float*)d_in[6];
  const float* b_m  = (const float*)d_in[7];
  const float* mean = (const float*)d_in[8];
  const float* sd   = (const float*)d_in[9];
  float* out = (float*)d_out;

  float* ws = (float*)d_ws;
  float* Wc    = ws;                 // 512*128
  float* biasv = ws + 65536;         // 512
  float* gbase = ws + 66048;         // 512
  float* h1    = ws + 66560;         // 128
  float* c1    = ws + 66688;         // 128
  float* rT    = ws + 66816;         // 128*1024
  float* h2T   = ws + 197888;        // 128*1024
  float* c2T   = ws + 328960;        // 128*1024
  float* h3T   = ws + 460032;        // 128*1024

  k_prep<<<68, 256, 0, stream>>>(W_ih, W_hh, b_ih, b_hh, Wc, biasv, gbase, h1, c1);

  // step 0 attention: q = h1 (broadcast) -> r0
  k_attn<<<BB, 256, 0, stream>>>(y, len, h1, 1, rT, W_m, b_m, mean, sd, nullptr, 0);
  // step 1 LSTM: gates = gbase + Wr*r0 -> h2, c2
  k_lstm<<<dim3(16, 16), 512, 0, stream>>>(W_ih, Wc, gbase, nullptr, c1, 1, rT, h2T, c2T);
  // step 1 attention: q = h2 -> r1
  k_attn<<<BB, 256, 0, stream>>>(y, len, h2T, 0, rT, W_m, b_m, mean, sd, nullptr, 0);
  // step 2 LSTM: gates = biasv + Wc*h2 + Wr*r1 -> h3
  k_lstm<<<dim3(16, 16), 512, 0, stream>>>(W_ih, Wc, biasv, h2T, c2T, 0, rT, h3T, nullptr);
  // step 2 attention + final projection
  k_attn<<<BB, 256, 0, stream>>>(y, len, h3T, 0, nullptr, W_m, b_m, mean, sd, out, 1);
}

// Round 4
// 63.615 us; speedup vs baseline: 2.8542x; 1.0594x over previous
//
#include <hip/hip_runtime.h>
#include <math.h>

#define BB 1024
#define NN 128
#define DD 128
#define GG 512   // 4*D

__device__ __forceinline__ float sigmoidf_(float x) { return 1.0f / (1.0f + expf(-x)); }

// ---------------------------------------------------------------------------
// k_prep: blocks 0..63 build Wc[512][128] = W_ih[:, :128] + W_hh.
// blocks 64..67: biasv = b_ih+b_hh, h1/c1 (step-0 LSTM from biases),
// gbase[512] = biasv + Wc·h1.
// ---------------------------------------------------------------------------
__global__ __launch_bounds__(256) void k_prep(
    const float* __restrict__ W_ih, const float* __restrict__ W_hh,
    const float* __restrict__ b_ih, const float* __restrict__ b_hh,
    float* __restrict__ Wc, float* __restrict__ biasv, float* __restrict__ gbase,
    float* __restrict__ h1, float* __restrict__ c1) {
  int b = blockIdx.x, t = threadIdx.x;
  if (b < 64) {
    int base = b * 1024;
    for (int i = t; i < 1024; i += 256) {
      int idx = base + i;
      int j = idx >> 7, d = idx & 127;
      Wc[idx] = W_ih[(j << 8) + d] + W_hh[idx];
    }
  } else {
    __shared__ float bv[GG];
    __shared__ float h1l[DD];
    for (int j = t; j < GG; j += 256) bv[j] = b_ih[j] + b_hh[j];
    __syncthreads();
    if (t < DD) {
      float cc = sigmoidf_(bv[t]) * tanhf(bv[256 + t]);
      float hh = sigmoidf_(bv[384 + t]) * tanhf(cc);
      h1l[t] = hh;
      if (b == 64) { c1[t] = cc; h1[t] = hh; }
    }
    if (b == 64) for (int j = t; j < GG; j += 256) biasv[j] = bv[j];
    __syncthreads();
    int j0 = (b - 64) * 128;
    if (t < 128) {
      int j = j0 + t;
      float acc = bv[j];
      const float* wi = W_ih + (j << 8);
      const float* wh = W_hh + (j << 7);
      #pragma unroll 8
      for (int d = 0; d < DD; ++d) acc = fmaf(wi[d] + wh[d], h1l[d], acc);
      gbase[j] = acc;
    }
  }
}

// ---------------------------------------------------------------------------
// k_attn v4: 256 threads / molecule, single pass, wave-uniform iteration skip,
// one-barrier two-level softmax, cross-g shuffle r-reduce, coalesced q/r I/O
// (row-major [B][d] state).
// ---------------------------------------------------------------------------
__global__ __launch_bounds__(256) void k_attn(
    const float* __restrict__ y, const int* __restrict__ lengths,
    const float* __restrict__ qsrc, int q_bcast,
    float* __restrict__ rN,
    const float* __restrict__ Wm, const float* __restrict__ bm,
    const float* __restrict__ mn, const float* __restrict__ sd,
    float* __restrict__ out, int is_final) {
  __shared__ float ql[DD];
  __shared__ float rp[4][DD];
  __shared__ float redm[4], reds[4], redf[4];

  int t = threadIdx.x, lane = t & 63, w = t >> 6;
  int sub = lane & 15, g = lane >> 4;
  int m = blockIdx.x;
  int len = lengths[m];
  const float* yb = y + (size_t)m * (NN * DD);
  int d0 = sub << 3;

  if (t < DD) ql[t] = q_bcast ? qsrc[t] : qsrc[m * DD + t];
  __syncthreads();

  float4 q0 = *(const float4*)&ql[d0];
  float4 q1 = *(const float4*)&ql[d0 + 4];

  float4 va[8], vb[8];
  float ee[8];
  int wbase = w << 2;

  #pragma unroll
  for (int it = 0; it < 8; ++it) {
    int nw = (it << 4) + wbase;            // wave-uniform base row
    if (nw < len) {
      int n = nw + g;
      int nc = (n < len) ? n : (len - 1);
      const float4* yr = (const float4*)(yb + nc * DD + d0);
      va[it] = yr[0];
      vb[it] = yr[1];
      float p = fmaf(va[it].x, q0.x, fmaf(va[it].y, q0.y,
                fmaf(va[it].z, q0.z, fmaf(va[it].w, q0.w,
                fmaf(vb[it].x, q1.x, fmaf(vb[it].y, q1.y,
                fmaf(vb[it].z, q1.z, vb[it].w * q1.w)))))));
      #pragma unroll
      for (int s = 1; s < 16; s <<= 1) p += __shfl_xor(p, s, 64);
      ee[it] = (n < len) ? p : -3.0e38f;
    } else {
      ee[it] = -3.0e38f;
    }
  }

  // ---- wave-local max + exp-sum ----
  float mloc = ee[0];
  #pragma unroll
  for (int it = 1; it < 8; ++it) mloc = fmaxf(mloc, ee[it]);
  #pragma unroll
  for (int s = 1; s < 64; s <<= 1) mloc = fmaxf(mloc, __shfl_xor(mloc, s, 64));

  float a[8];
  float sl = 0.0f;
  #pragma unroll
  for (int it = 0; it < 8; ++it) { a[it] = expf(ee[it] - mloc); sl += a[it]; }
  #pragma unroll
  for (int s = 1; s < 64; s <<= 1) sl += __shfl_xor(sl, s, 64);
  if (lane == 0) { redm[w] = mloc; reds[w] = sl; }
  __syncthreads();

  float m0_ = redm[0], m1_ = redm[1], m2_ = redm[2], m3_ = redm[3];
  float mx = fmaxf(fmaxf(m0_, m1_), fmaxf(m2_, m3_));
  float Zraw = reds[0] * expf(m0_ - mx) + reds[1] * expf(m1_ - mx) +
               reds[2] * expf(m2_ - mx) + reds[3] * expf(m3_ - mx);
  float wscale = expf(mloc - mx) * (16.0f / Zraw);   // folds invZ + 16x dup

  // ---- weighted sum from registers ----
  float4 r0 = {0.f, 0.f, 0.f, 0.f}, r1 = {0.f, 0.f, 0.f, 0.f};
  #pragma unroll
  for (int it = 0; it < 8; ++it) {
    int nw = (it << 4) + wbase;
    if (nw < len) {
      float av = a[it];
      r0.x = fmaf(av, va[it].x, r0.x); r0.y = fmaf(av, va[it].y, r0.y);
      r0.z = fmaf(av, va[it].z, r0.z); r0.w = fmaf(av, va[it].w, r0.w);
      r1.x = fmaf(av, vb[it].x, r1.x); r1.y = fmaf(av, vb[it].y, r1.y);
      r1.z = fmaf(av, vb[it].z, r1.z); r1.w = fmaf(av, vb[it].w, r1.w);
    }
  }
  r0.x *= wscale; r0.y *= wscale; r0.z *= wscale; r0.w *= wscale;
  r1.x *= wscale; r1.y *= wscale; r1.z *= wscale; r1.w *= wscale;

  // cross-g reduce (lanes differing in bits 4,5 share the same d-slice)
  #pragma unroll
  for (int s = 16; s < 64; s <<= 1) {
    r0.x += __shfl_xor(r0.x, s, 64); r0.y += __shfl_xor(r0.y, s, 64);
    r0.z += __shfl_xor(r0.z, s, 64); r0.w += __shfl_xor(r0.w, s, 64);
    r1.x += __shfl_xor(r1.x, s, 64); r1.y += __shfl_xor(r1.y, s, 64);
    r1.z += __shfl_xor(r1.z, s, 64); r1.w += __shfl_xor(r1.w, s, 64);
  }
  if (g == 0) {
    *(float4*)&rp[w][d0] = r0;
    *(float4*)&rp[w][d0 + 4] = r1;
  }
  __syncthreads();

  float r_ = 0.0f;
  if (t < DD) {
    r_ = rp[0][t] + rp[1][t] + rp[2][t] + rp[3][t];
    if (!is_final) rN[m * DD + t] = r_;
  }
  if (is_final) {
    float part = (t < DD) ? (Wm[t] * ql[t] + Wm[DD + t] * r_) : 0.0f;
    #pragma unroll
    for (int s = 1; s < 64; s <<= 1) part += __shfl_xor(part, s, 64);
    if (lane == 0) redf[w] = part;
    __syncthreads();
    if (t == 0) out[m] = (redf[0] + redf[1] + redf[2] + redf[3] + bm[0]) * sd[0] + mn[0];
  }
}

// ---------------------------------------------------------------------------
// k_lstm v4: 512 threads (8 waves), block = 64 molecules x 8 hidden indices.
// Row-major [B][d] x panels staged into LDS with pad-129 (free 2-way banks).
// Wave wid owns hidden index jb = by*8+wid (gate rows jb+{0,128,256,384}),
// weights via wave-uniform scalar loads; lane = molecule.
// h written to row-major hN via small LDS transpose tile; c stays [d][B].
// ---------------------------------------------------------------------------
__global__ __launch_bounds__(512) void k_lstm(
    const float* __restrict__ W_ih, const float* __restrict__ Wc,
    const float* __restrict__ gb,
    const float* __restrict__ h_inN,
    const float* __restrict__ c_in, int c_bcast,
    const float* __restrict__ rNin,
    float* __restrict__ h_outN, float* __restrict__ c_outT) {
  __shared__ float xl[64 * 129];
  __shared__ float ht[64 * 9];
  int t = threadIdx.x;
  int ml = t & 63, wid = t >> 6;
  int m0 = blockIdx.x << 6;
  int m = m0 + ml;
  int jb = __builtin_amdgcn_readfirstlane((blockIdx.y << 3) + wid);  // 0..127

  float ai = gb[jb], af = gb[DD + jb], ag = gb[2 * DD + jb], ao = gb[3 * DD + jb];

  if (h_inN) {
    #pragma unroll
    for (int k = 0; k < 16; ++k) {
      int i = (k << 9) + t;
      int mm = i >> 7, dd = i & 127;
      xl[mm * 129 + dd] = h_inN[(m0 + mm) * DD + dd];
    }
    __syncthreads();
    const float* w0 = Wc + jb * DD;
    const float* w1 = Wc + (128 + jb) * DD;
    const float* w2 = Wc + (256 + jb) * DD;
    const float* w3 = Wc + (384 + jb) * DD;
    #pragma unroll 8
    for (int d = 0; d < DD; ++d) {
      float xd = xl[ml * 129 + d];
      ai = fmaf(w0[d], xd, ai); af = fmaf(w1[d], xd, af);
      ag = fmaf(w2[d], xd, ag); ao = fmaf(w3[d], xd, ao);
    }
    __syncthreads();   // done reading before restage
  }

  #pragma unroll
  for (int k = 0; k < 16; ++k) {
    int i = (k << 9) + t;
    int mm = i >> 7, dd = i & 127;
    xl[mm * 129 + dd] = rNin[(m0 + mm) * DD + dd];
  }
  __syncthreads();
  {
    const float* w0 = W_ih + jb * 256 + 128;
    const float* w1 = W_ih + (128 + jb) * 256 + 128;
    const float* w2 = W_ih + (256 + jb) * 256 + 128;
    const float* w3 = W_ih + (384 + jb) * 256 + 128;
    #pragma unroll 8
    for (int d = 0; d < DD; ++d) {
      float xd = xl[ml * 129 + d];
      ai = fmaf(w0[d], xd, ai); af = fmaf(w1[d], xd, af);
      ag = fmaf(w2[d], xd, ag); ao = fmaf(w3[d], xd, ao);
    }
  }

  float cin = c_bcast ? c_in[jb] : c_in[jb * BB + m];
  float cc = fmaf(sigmoidf_(af), cin, sigmoidf_(ai) * tanhf(ag));
  float hh = sigmoidf_(ao) * tanhf(cc);
  ht[ml * 9 + wid] = hh;
  if (c_outT) c_outT[jb * BB + m] = cc;
  __syncthreads();
  {
    int jj = t & 7, mm = t >> 3;
    h_outN[(m0 + mm) * DD + (blockIdx.y << 3) + jj] = ht[mm * 9 + jj];
  }
}

// ---------------------------------------------------------------------------
extern "C" void kernel_launch(void* const* d_in, const int* in_sizes, int n_in,
                              void* d_out, int out_size, void* d_ws, size_t ws_size,
                              hipStream_t stream) {
  const float* y    = (const float*)d_in[0];
  const int*   len  = (const int*)  d_in[1];
  const float* W_ih = (const float*)d_in[2];
  const float* W_hh = (const float*)d_in[3];
  const float* b_ih = (const float*)d_in[4];
  const float* b_hh = (const float*)d_in[5];
  const float* W_m  = (const float*)d_in[6];
  const float* b_m  = (const float*)d_in[7];
  const float* mean = (const float*)d_in[8];
  const float* sd   = (const float*)d_in[9];
  float* out = (float*)d_out;

  float* ws = (float*)d_ws;
  float* Wc    = ws;                 // 512*128
  float* biasv = ws + 65536;         // 512
  float* gbase = ws + 66048;         // 512
  float* h1    = ws + 66560;         // 128
  float* c1    = ws + 66688;         // 128
  float* rN    = ws + 66816;         // 1024*128 row-major
  float* h2N   = ws + 197888;        // 1024*128 row-major
  float* c2T   = ws + 328960;        // 128*1024 transposed
  float* h3N   = ws + 460032;        // 1024*128 row-major

  k_prep<<<68, 256, 0, stream>>>(W_ih, W_hh, b_ih, b_hh, Wc, biasv, gbase, h1, c1);

  // step 0 attention: q = h1 (broadcast) -> r0
  k_attn<<<BB, 256, 0, stream>>>(y, len, h1, 1, rN, W_m, b_m, mean, sd, nullptr, 0);
  // step 1 LSTM: gates = gbase + Wr*r0 -> h2, c2
  k_lstm<<<dim3(16, 16), 512, 0, stream>>>(W_ih, Wc, gbase, nullptr, c1, 1, rN, h2N, c2T);
  // step 1 attention: q = h2 -> r1
  k_attn<<<BB, 256, 0, stream>>>(y, len, h2N, 0, rN, W_m, b_m, mean, sd, nullptr, 0);
  // step 2 LSTM: gates = biasv + Wc*h2 + Wr*r1 -> h3
  k_lstm<<<dim3(16, 16), 512, 0, stream>>>(W_ih, Wc, biasv, h2N, c2T, 0, rN, h3N, nullptr);
  // step 2 attention + final projection
  k_attn<<<BB, 256, 0, stream>>>(y, len, h3N, 0, nullptr, W_m, b_m, mean, sd, out, 1);
}

// Round 5
// 61.346 us; speedup vs baseline: 2.9598x; 1.0370x over previous
//
#include <hip/hip_runtime.h>
#include <math.h>

#define BB 1024
#define NN 128
#define DD 128

__device__ __forceinline__ float sigmoidf_(float x) { return 1.0f / (1.0f + expf(-x)); }

// ---------------------------------------------------------------------------
// k_attn v5: 512 threads = 2 molecules (mA = bx, mB = 1023-bx), 4 waves each.
// Per molecule-half: 16 UNCONDITIONAL clamped float4-pair loads issued first,
// then wave-uniform compute-skip. One-barrier two-level softmax. q from
// row-major hN, or computed from biases (h1) when qsrc == nullptr.
// ---------------------------------------------------------------------------
__global__ __launch_bounds__(512) void k_attn(
    const float* __restrict__ y, const int* __restrict__ lengths,
    const float* __restrict__ qsrc,
    const float* __restrict__ b_ih, const float* __restrict__ b_hh,
    float* __restrict__ rN,
    const float* __restrict__ Wm, const float* __restrict__ bm,
    const float* __restrict__ mn, const float* __restrict__ sd,
    float* __restrict__ out, int is_final) {
  __shared__ float ql[2][DD];
  __shared__ float rp[2][4][DD];
  __shared__ float redm[2][4], reds[2][4], redf[2][4];

  int t = threadIdx.x, lane = t & 63, w = t >> 6;
  int h = w >> 2, w4 = w & 3;
  int sub = lane & 15, g = lane >> 4;
  int m = h ? (1023 - (int)blockIdx.x) : (int)blockIdx.x;
  int len = lengths[m];
  const float* yb = y + (size_t)m * (NN * DD);
  int d0 = sub << 3;
  int th = t & 255;

  if (th < DD) {
    if (qsrc) {
      ql[h][th] = qsrc[m * DD + th];
    } else {
      float bv0 = b_ih[th] + b_hh[th];
      float bvg = b_ih[256 + th] + b_hh[256 + th];
      float bvo = b_ih[384 + th] + b_hh[384 + th];
      float cc = sigmoidf_(bv0) * tanhf(bvg);
      ql[h][th] = sigmoidf_(bvo) * tanhf(cc);
    }
  }
  __syncthreads();

  float4 q0 = *(const float4*)&ql[h][d0];
  float4 q1 = *(const float4*)&ql[h][d0 + 4];

  // ---- load phase: all 16 loads issued unconditionally ----
  float4 va[8], vb[8];
  int wbase = w4 << 2;
  #pragma unroll
  for (int it = 0; it < 8; ++it) {
    int n = (it << 4) + wbase + g;
    int nc = (n < len) ? n : (len - 1);
    const float4* yr = (const float4*)(yb + nc * DD + d0);
    va[it] = yr[0];
    vb[it] = yr[1];
  }

  // ---- compute phase: wave-uniform skip ----
  float ee[8];
  #pragma unroll
  for (int it = 0; it < 8; ++it) {
    int nw = (it << 4) + wbase;
    if (nw < len) {
      int n = nw + g;
      float p = fmaf(va[it].x, q0.x, fmaf(va[it].y, q0.y,
                fmaf(va[it].z, q0.z, fmaf(va[it].w, q0.w,
                fmaf(vb[it].x, q1.x, fmaf(vb[it].y, q1.y,
                fmaf(vb[it].z, q1.z, vb[it].w * q1.w)))))));
      #pragma unroll
      for (int s = 1; s < 16; s <<= 1) p += __shfl_xor(p, s, 64);
      ee[it] = (n < len) ? p : -3.0e38f;
    } else {
      ee[it] = -3.0e38f;
    }
  }

  // ---- wave-local max + exp-sum, one barrier ----
  float mloc = ee[0];
  #pragma unroll
  for (int it = 1; it < 8; ++it) mloc = fmaxf(mloc, ee[it]);
  #pragma unroll
  for (int s = 1; s < 64; s <<= 1) mloc = fmaxf(mloc, __shfl_xor(mloc, s, 64));

  float a[8];
  float sl = 0.0f;
  #pragma unroll
  for (int it = 0; it < 8; ++it) { a[it] = expf(ee[it] - mloc); sl += a[it]; }
  #pragma unroll
  for (int s = 1; s < 64; s <<= 1) sl += __shfl_xor(sl, s, 64);
  if (lane == 0) { redm[h][w4] = mloc; reds[h][w4] = sl; }
  __syncthreads();

  float m0_ = redm[h][0], m1_ = redm[h][1], m2_ = redm[h][2], m3_ = redm[h][3];
  float mx = fmaxf(fmaxf(m0_, m1_), fmaxf(m2_, m3_));
  float Zraw = reds[h][0] * expf(m0_ - mx) + reds[h][1] * expf(m1_ - mx) +
               reds[h][2] * expf(m2_ - mx) + reds[h][3] * expf(m3_ - mx);
  float wscale = expf(mloc - mx) * (16.0f / Zraw);   // folds invZ + 16x dup

  // ---- weighted sum from registers (skip dead iterations) ----
  float4 r0 = {0.f, 0.f, 0.f, 0.f}, r1 = {0.f, 0.f, 0.f, 0.f};
  #pragma unroll
  for (int it = 0; it < 8; ++it) {
    int nw = (it << 4) + wbase;
    if (nw < len) {
      float av = a[it];
      r0.x = fmaf(av, va[it].x, r0.x); r0.y = fmaf(av, va[it].y, r0.y);
      r0.z = fmaf(av, va[it].z, r0.z); r0.w = fmaf(av, va[it].w, r0.w);
      r1.x = fmaf(av, vb[it].x, r1.x); r1.y = fmaf(av, vb[it].y, r1.y);
      r1.z = fmaf(av, vb[it].z, r1.z); r1.w = fmaf(av, vb[it].w, r1.w);
    }
  }
  r0.x *= wscale; r0.y *= wscale; r0.z *= wscale; r0.w *= wscale;
  r1.x *= wscale; r1.y *= wscale; r1.z *= wscale; r1.w *= wscale;

  // cross-g reduce (lanes differing in bits 4,5 hold the same d-slice)
  #pragma unroll
  for (int s = 16; s < 64; s <<= 1) {
    r0.x += __shfl_xor(r0.x, s, 64); r0.y += __shfl_xor(r0.y, s, 64);
    r0.z += __shfl_xor(r0.z, s, 64); r0.w += __shfl_xor(r0.w, s, 64);
    r1.x += __shfl_xor(r1.x, s, 64); r1.y += __shfl_xor(r1.y, s, 64);
    r1.z += __shfl_xor(r1.z, s, 64); r1.w += __shfl_xor(r1.w, s, 64);
  }
  if (g == 0) {
    *(float4*)&rp[h][w4][d0] = r0;
    *(float4*)&rp[h][w4][d0 + 4] = r1;
  }
  __syncthreads();

  float r_ = 0.0f;
  if (th < DD) {
    r_ = rp[h][0][th] + rp[h][1][th] + rp[h][2][th] + rp[h][3][th];
    if (!is_final) rN[m * DD + th] = r_;
  }
  if (is_final) {
    float part = (th < DD) ? (Wm[th] * ql[h][th] + Wm[DD + th] * r_) : 0.0f;
    #pragma unroll
    for (int s = 1; s < 64; s <<= 1) part += __shfl_xor(part, s, 64);
    if (lane == 0) redf[h][w4] = part;
    __syncthreads();
    if (th == 0)
      out[m] = (redf[h][0] + redf[h][1] + redf[h][2] + redf[h][3] + bm[0]) * sd[0] + mn[0];
  }
}

// ---------------------------------------------------------------------------
// k_lstm v5: 512 threads (8 waves) = 64 molecules x 8 hidden indices.
// step 1: gates = [biasv + Wc*h1] + Wr*r0 ; gbase slice computed in-block
//         (h1 from biases, distributed 128-dots); bx==0 blocks also write
//         their Wc rows (= W_ih[:,:128]+W_hh) for step 2 to consume.
// step 2: gates = biasv + Wc*h2 + Wr*r1 (Wc precomputed by step 1).
// x panels staged in LDS (pad 129); weights via wave-uniform scalar streams.
// ---------------------------------------------------------------------------
__global__ __launch_bounds__(512) void k_lstm(
    const float* __restrict__ W_ih, const float* __restrict__ W_hh,
    const float* __restrict__ b_ih, const float* __restrict__ b_hh,
    float* __restrict__ Wc,
    const float* __restrict__ h_inN,
    const float* __restrict__ cT,
    const float* __restrict__ rNin,
    float* __restrict__ h_outN, float* __restrict__ c_outT, int step) {
  __shared__ float xl[64 * 129];
  __shared__ float h1l[DD];
  __shared__ float ht[64 * 9];
  int t = threadIdx.x, lane = t & 63, wid = t >> 6;
  int m0 = (int)blockIdx.x << 6, m = m0 + lane;
  int jb = __builtin_amdgcn_readfirstlane(((int)blockIdx.y << 3) + wid);  // 0..127

  float ai, af, ag, ao, cin;

  if (step == 1) {
    if (t < DD) {
      float bv0 = b_ih[t] + b_hh[t];
      float bvg = b_ih[256 + t] + b_hh[256 + t];
      float bvo = b_ih[384 + t] + b_hh[384 + t];
      float cc = sigmoidf_(bv0) * tanhf(bvg);
      h1l[t] = sigmoidf_(bvo) * tanhf(cc);
    }
    __syncthreads();
    int d = lane << 1;
    float acc4[4];
    #pragma unroll
    for (int gi = 0; gi < 4; ++gi) {
      int j = jb + (gi << 7);
      float2 wih = *(const float2*)&W_ih[j * 256 + d];
      float2 whh = *(const float2*)&W_hh[(j << 7) + d];
      float s0 = wih.x + whh.x, s1 = wih.y + whh.y;
      if (blockIdx.x == 0) {               // sideline: materialize Wc rows
        Wc[(j << 7) + d] = s0;
        Wc[(j << 7) + d + 1] = s1;
      }
      float part = fmaf(s0, h1l[d], s1 * h1l[d + 1]);
      #pragma unroll
      for (int s = 1; s < 64; s <<= 1) part += __shfl_xor(part, s, 64);
      acc4[gi] = part + b_ih[j] + b_hh[j];
    }
    ai = acc4[0]; af = acc4[1]; ag = acc4[2]; ao = acc4[3];
    cin = sigmoidf_(b_ih[jb] + b_hh[jb]) *
          tanhf(b_ih[256 + jb] + b_hh[256 + jb]);
  } else {
    ai = b_ih[jb] + b_hh[jb];
    af = b_ih[128 + jb] + b_hh[128 + jb];
    ag = b_ih[256 + jb] + b_hh[256 + jb];
    ao = b_ih[384 + jb] + b_hh[384 + jb];
    cin = cT[(jb << 10) + m];
    // h-phase
    #pragma unroll
    for (int k = 0; k < 16; ++k) {
      int i = (k << 9) + t;
      int mm = i >> 7, dd = i & 127;
      xl[mm * 129 + dd] = h_inN[(m0 + mm) * DD + dd];
    }
    __syncthreads();
    const float* w0 = Wc + (jb << 7);
    const float* w1 = Wc + ((128 + jb) << 7);
    const float* w2 = Wc + ((256 + jb) << 7);
    const float* w3 = Wc + ((384 + jb) << 7);
    #pragma unroll 8
    for (int dd = 0; dd < DD; ++dd) {
      float xd = xl[lane * 129 + dd];
      ai = fmaf(w0[dd], xd, ai); af = fmaf(w1[dd], xd, af);
      ag = fmaf(w2[dd], xd, ag); ao = fmaf(w3[dd], xd, ao);
    }
    __syncthreads();   // done reading before restage
  }

  // ---- r-phase (both steps) ----
  #pragma unroll
  for (int k = 0; k < 16; ++k) {
    int i = (k << 9) + t;
    int mm = i >> 7, dd = i & 127;
    xl[mm * 129 + dd] = rNin[(m0 + mm) * DD + dd];
  }
  __syncthreads();
  {
    const float* w0 = W_ih + jb * 256 + 128;
    const float* w1 = W_ih + (128 + jb) * 256 + 128;
    const float* w2 = W_ih + (256 + jb) * 256 + 128;
    const float* w3 = W_ih + (384 + jb) * 256 + 128;
    #pragma unroll 8
    for (int dd = 0; dd < DD; ++dd) {
      float xd = xl[lane * 129 + dd];
      ai = fmaf(w0[dd], xd, ai); af = fmaf(w1[dd], xd, af);
      ag = fmaf(w2[dd], xd, ag); ao = fmaf(w3[dd], xd, ao);
    }
  }

  float cc = fmaf(sigmoidf_(af), cin, sigmoidf_(ai) * tanhf(ag));
  float hh = sigmoidf_(ao) * tanhf(cc);
  ht[lane * 9 + wid] = hh;
  if (c_outT) c_outT[(jb << 10) + m] = cc;
  __syncthreads();
  {
    int jj = t & 7, mm = t >> 3;
    h_outN[(m0 + mm) * DD + ((int)blockIdx.y << 3) + jj] = ht[mm * 9 + jj];
  }
}

// ---------------------------------------------------------------------------
extern "C" void kernel_launch(void* const* d_in, const int* in_sizes, int n_in,
                              void* d_out, int out_size, void* d_ws, size_t ws_size,
                              hipStream_t stream) {
  const float* y    = (const float*)d_in[0];
  const int*   len  = (const int*)  d_in[1];
  const float* W_ih = (const float*)d_in[2];
  const float* W_hh = (const float*)d_in[3];
  const float* b_ih = (const float*)d_in[4];
  const float* b_hh = (const float*)d_in[5];
  const float* W_m  = (const float*)d_in[6];
  const float* b_m  = (const float*)d_in[7];
  const float* mean = (const float*)d_in[8];
  const float* sd   = (const float*)d_in[9];
  float* out = (float*)d_out;

  float* ws = (float*)d_ws;
  float* Wc  = ws;                 // 512*128
  float* rN  = ws + 65536;         // 1024*128 row-major
  float* h2N = ws + 196608;        // 1024*128 row-major
  float* c2T = ws + 327680;        // 128*1024 transposed
  float* h3N = ws + 458752;        // 1024*128 row-major

  // step 0 attention (q = h1 computed in-block) -> r0
  k_attn<<<512, 512, 0, stream>>>(y, len, nullptr, b_ih, b_hh, rN,
                                  W_m, b_m, mean, sd, nullptr, 0);
  // step 1 LSTM (gbase in-block; writes Wc sideline) -> h2, c2
  k_lstm<<<dim3(16, 16), 512, 0, stream>>>(W_ih, W_hh, b_ih, b_hh, Wc,
                                           nullptr, nullptr, rN, h2N, c2T, 1);
  // step 1 attention: q = h2 -> r1
  k_attn<<<512, 512, 0, stream>>>(y, len, h2N, b_ih, b_hh, rN,
                                  W_m, b_m, mean, sd, nullptr, 0);
  // step 2 LSTM: gates = biasv + Wc*h2 + Wr*r1 -> h3
  k_lstm<<<dim3(16, 16), 512, 0, stream>>>(W_ih, W_hh, b_ih, b_hh, Wc,
                                           h2N, c2T, rN, h3N, nullptr, 2);
  // step 2 attention + final projection
  k_attn<<<512, 512, 0, stream>>>(y, len, h3N, b_ih, b_hh, nullptr,
                                  W_m, b_m, mean, sd, out, 1);
}